// Round 5
// baseline (548.122 us; speedup 1.0000x reference)
//
#include <hip/hip_runtime.h>
#include <math.h>

// Problem constants
#define BATCH   8192
#define IN_DIM  1024
#define LAT     256
#define NEMB    8192

#define TAU 3e-3f   // flag margin; score err sigma ~2.8e-4 (fp16-B rounding), TAU ~ 10 sigma

typedef _Float16 f16x8 __attribute__((ext_vector_type(8)));
typedef _Float16 f16x4 __attribute__((ext_vector_type(4)));
typedef float f32x16_t __attribute__((ext_vector_type(16)));

typedef __attribute__((address_space(1))) const unsigned int gu32_t;
typedef __attribute__((address_space(3))) unsigned int lu32_t;

#define ZLO ((size_t)BATCH * LAT)

// order-preserving float<->u32 transform
__device__ __forceinline__ unsigned int ford(float x) {
  unsigned int u = __float_as_uint(x);
  return (u & 0x80000000u) ? ~u : (u | 0x80000000u);
}
__device__ __forceinline__ float funord(unsigned int t) {
  unsigned int u = (t & 0x80000000u) ? (t & 0x7FFFFFFFu) : ~t;
  return __uint_as_float(u);
}

// ---------------------------------------------------------------------------
// Per-code inverse norms: one wave per embedding row.
// ---------------------------------------------------------------------------
__global__ __launch_bounds__(256) void emb_norms(
    const float* __restrict__ emb, float* __restrict__ inv_norm) {
  int row = blockIdx.x * 4 + (threadIdx.x >> 6);
  int lane = threadIdx.x & 63;
  const float* p = emb + (size_t)row * LAT;
  float s = 0.f;
#pragma unroll
  for (int t = 0; t < 4; ++t) {
    float v = p[lane + 64 * t];
    s += v * v;
  }
#pragma unroll
  for (int off = 32; off; off >>= 1) s += __shfl_xor(s, off);
  if (lane == 0) inv_norm[row] = 1.0f / sqrtf(s);
}

// ---------------------------------------------------------------------------
// Split fp32 [R x K] (optionally scaled per-row) into fp16 hi (+ optional lo)
// in MFMA-32x32x16 fragment order:
//   frag block g=(tile,kb): lane l -> elem [tile*32+(l&31)][kb*16+(l>>5)*8+j]
//   stored at dst[(g*64+l)*8 + j]; lo at dst + lo_off (= R*K) if write_lo.
// ---------------------------------------------------------------------------
__global__ __launch_bounds__(256) void split16(
    const float* __restrict__ src, const float* __restrict__ inv_norm,
    _Float16* __restrict__ dst, size_t lo_off, int KD, int write_lo) {
  int gw = (blockIdx.x * 256 + threadIdx.x) >> 6;
  int l = threadIdx.x & 63;
  int tile = gw / KD, kb = gw % KD;
  int row = tile * 32 + (l & 31);
  int k = kb * 16 + (l >> 5) * 8;
  const float* p = src + (size_t)row * (KD * 16) + k;
  float scale = inv_norm ? inv_norm[row] : 1.0f;
  f16x8 h, lo;
#pragma unroll
  for (int j = 0; j < 8; ++j) {
    float v = p[j] * scale;
    _Float16 hh = (_Float16)v;
    h[j] = hh;
    lo[j] = (_Float16)(v - (float)hh);
  }
  size_t o = ((size_t)gw * 64 + l) * 8;
  *(f16x8*)(dst + o) = h;
  if (write_lo) *(f16x8*)(dst + lo_off + o) = lo;
}

// ---------------------------------------------------------------------------
// Split-fp16 MFMA GEMM, small-M blocking: C[M][N] = A@Bw^T + bias.
// Block: 32 rows x 128 cols, 4 waves, wave w owns n-tile w. K-slices of 64.
// A: fp32, hi/lo split in-kernel (ds_write); B: pre-split frag fp16 via
// global_load_lds. B (<=1MB) stays L2-resident across all blocks.
// LDS 40KB -> 4 blocks/CU. 3 MFMAs per k-step (ah*bh + ah*bl + al*bh).
// ---------------------------------------------------------------------------
__global__ __launch_bounds__(256) void gemm16s(
    const float* __restrict__ A, const _Float16* __restrict__ Bfrag,
    size_t b_lo_off, const float* __restrict__ bias, float* __restrict__ C,
    int N, int K) {
  __shared__ char lds[8192 + 32768];  // A: [prec2][ks4]x1KB; B: [nt4][prec2][ks4]x1KB
  const int tid = threadIdx.x;
  const int l = tid & 63;
  const int w = tid >> 6;
  const int rb = blockIdx.y * 32;
  const int nb = blockIdx.x;  // 128-col block
  const int KD = K >> 4;

  f32x16_t acc = (f32x16_t)0.0f;

  for (int s = 0; s < (K >> 6); ++s) {
    // B staging: wave w stages its own n-tile (8 chunks of 1KB)
#pragma unroll
    for (int i = 0; i < 8; ++i) {
      int prec = i >> 2, ks = i & 3;
      const _Float16* src = Bfrag + (size_t)prec * b_lo_off +
          ((size_t)((nb * 4 + w) * KD + s * 4 + ks) * 64 + l) * 8;
      __builtin_amdgcn_global_load_lds(
          (gu32_t*)src, (lu32_t*)(lds + 8192 + (w * 8 + i) * 1024 + l * 16),
          16, 0, 0);
    }
    // A staging: load fp32, split hi/lo, ds_write in frag order
#pragma unroll
    for (int t = 0; t < 2; ++t) {
      int flat = t * 256 + tid;
      int r = flat >> 4, c4 = flat & 15;
      float4 v = *(const float4*)&A[(size_t)(rb + r) * K + s * 64 + 4 * c4];
      int kk = 4 * c4;
      int ks = kk >> 4, j = kk & 7;
      int lane2 = r + 32 * ((kk >> 3) & 1);
      f16x4 hv, lv;
      float vv[4] = {v.x, v.y, v.z, v.w};
#pragma unroll
      for (int e = 0; e < 4; ++e) {
        _Float16 h = (_Float16)vv[e];
        hv[e] = h;
        lv[e] = (_Float16)(vv[e] - (float)h);
      }
      int base = ks * 1024 + lane2 * 16 + j * 2;
      *(f16x4*)(lds + base) = hv;
      *(f16x4*)(lds + base + 4096) = lv;
    }
    __syncthreads();
#pragma unroll
    for (int ks = 0; ks < 4; ++ks) {
      f16x8 ah = *(const f16x8*)(lds + ks * 1024 + l * 16);
      f16x8 al = *(const f16x8*)(lds + 4096 + ks * 1024 + l * 16);
      f16x8 bh = *(const f16x8*)(lds + 8192 + (w * 8 + ks) * 1024 + l * 16);
      f16x8 bl = *(const f16x8*)(lds + 8192 + (w * 8 + 4 + ks) * 1024 + l * 16);
      acc = __builtin_amdgcn_mfma_f32_32x32x16_f16(ah, bh, acc, 0, 0, 0);
      acc = __builtin_amdgcn_mfma_f32_32x32x16_f16(ah, bl, acc, 0, 0, 0);
      acc = __builtin_amdgcn_mfma_f32_32x32x16_f16(al, bh, acc, 0, 0, 0);
    }
    __syncthreads();
  }

  int col = nb * 128 + w * 32 + (l & 31);
  float bv = bias[col];
#pragma unroll
  for (int r = 0; r < 16; ++r) {
    int row = rb + (r & 3) + 8 * (r >> 2) + 4 * (l >> 5);
    C[(size_t)row * N + col] = acc[r] + bv;
  }
}

// ---------------------------------------------------------------------------
// Scorer v3: s = z . e_hat, A(z)=hi/lo fp16 (2 MFMAs), B(e_hat)=hi fp16.
// Grid: 1024 blocks 1D; csplit = bid&7 (same csplit -> same XCD under
// round-robin dispatch => 512KB efrag slice L2-resident), rowblock = bid>>3.
// Block: 64 rows. A staged ONCE into 64KB LDS (one barrier total); e-hat
// streamed straight to VGPRs (16x dwordx4 prefetch per 32-code chunk) --
// no LDS round-trip, no barriers in the main loop. Wave w owns codes
// [csplit*1024 + w*256, +256) in 8 chunks of 32; per-row top-2 fold.
// ---------------------------------------------------------------------------
__global__ __launch_bounds__(256, 2) void score_mfma(
    const _Float16* __restrict__ zfrag, const _Float16* __restrict__ efrag,
    unsigned long long* __restrict__ cand1, unsigned int* __restrict__ cand2) {
  __shared__ char lds[65536];  // A: c = mt*32 + prec*16 + kb, 64 chunks x 1KB
  const int tid = threadIdx.x;
  const int l = tid & 63;
  const int w = tid >> 6;
  const int bid = blockIdx.x;
  const int csplit = bid & 7;
  const int rowblock = bid >> 3;  // 64 rows

#pragma unroll
  for (int i = 0; i < 16; ++i) {
    int c = w * 16 + i;
    int mt = c >> 5, prec = (c >> 4) & 1, kb = c & 15;
    const _Float16* src = zfrag + (size_t)prec * ZLO +
        ((size_t)((rowblock * 2 + mt) * 16 + kb) * 64 + l) * 8;
    __builtin_amdgcn_global_load_lds(
        (gu32_t*)src, (lu32_t*)(lds + c * 1024 + l * 16), 16, 0, 0);
  }
  __syncthreads();

  float b1[2][16], b2[2][16];
  int i1[2][16];
#pragma unroll
  for (int mt = 0; mt < 2; ++mt)
#pragma unroll
    for (int r = 0; r < 16; ++r) {
      b1[mt][r] = -INFINITY;
      b2[mt][r] = -INFINITY;
      i1[mt][r] = 0;
    }

  for (int chunk = 0; chunk < 8; ++chunk) {
    const int etile = csplit * 32 + w * 8 + chunk;
    const _Float16* ebase = efrag + (size_t)etile * 8192 + (size_t)l * 8;
    f16x8 bh[16];
#pragma unroll
    for (int kb = 0; kb < 16; ++kb)
      bh[kb] = *(const f16x8*)(ebase + kb * 512);

    f32x16_t acc0 = (f32x16_t)0.0f, acc1 = (f32x16_t)0.0f;
#pragma unroll
    for (int kb = 0; kb < 16; ++kb) {
      f16x8 ah0 = *(const f16x8*)(lds + kb * 1024 + l * 16);
      f16x8 al0 = *(const f16x8*)(lds + (16 + kb) * 1024 + l * 16);
      f16x8 ah1 = *(const f16x8*)(lds + (32 + kb) * 1024 + l * 16);
      f16x8 al1 = *(const f16x8*)(lds + (48 + kb) * 1024 + l * 16);
      acc0 = __builtin_amdgcn_mfma_f32_32x32x16_f16(ah0, bh[kb], acc0, 0, 0, 0);
      acc0 = __builtin_amdgcn_mfma_f32_32x32x16_f16(al0, bh[kb], acc0, 0, 0, 0);
      acc1 = __builtin_amdgcn_mfma_f32_32x32x16_f16(ah1, bh[kb], acc1, 0, 0, 0);
      acc1 = __builtin_amdgcn_mfma_f32_32x32x16_f16(al1, bh[kb], acc1, 0, 0, 0);
    }

    const int col = (etile << 5) + (l & 31);
#pragma unroll
    for (int r = 0; r < 16; ++r) {
      float s0 = acc0[r];
      if (s0 > b1[0][r]) {
        b2[0][r] = b1[0][r];
        b1[0][r] = s0;
        i1[0][r] = col;
      } else {
        b2[0][r] = fmaxf(b2[0][r], s0);
      }
      float s1 = acc1[r];
      if (s1 > b1[1][r]) {
        b2[1][r] = b1[1][r];
        b1[1][r] = s1;
        i1[1][r] = col;
      } else {
        b2[1][r] = fmaxf(b2[1][r], s1);
      }
    }
  }

  // cross-lane top-2 merge over 32 cols (ties -> lower idx), write slot
  const int slot = csplit * 4 + w;
#pragma unroll
  for (int mt = 0; mt < 2; ++mt)
#pragma unroll
    for (int r = 0; r < 16; ++r) {
      float v1 = b1[mt][r], v2 = b2[mt][r];
      int vi = i1[mt][r];
#pragma unroll
      for (int m = 1; m < 32; m <<= 1) {
        float o1 = __shfl_xor(v1, m);
        int oi = __shfl_xor(vi, m);
        float o2 = __shfl_xor(v2, m);
        float n2 = fmaxf(fminf(v1, o1), fmaxf(v2, o2));
        if (o1 > v1 || (o1 == v1 && oi < vi)) {
          v1 = o1;
          vi = oi;
        }
        v2 = n2;
      }
      if ((l & 31) == 0) {
        int row = rowblock * 64 + mt * 32 + (r & 3) + 8 * (r >> 2) + 4 * (l >> 5);
        cand1[(size_t)row * 32 + slot] =
            ((unsigned long long)ford(v1) << 32) |
            (unsigned long long)(unsigned int)(NEMB - 1 - vi);
        cand2[(size_t)row * 32 + slot] = ford(v2);
      }
    }
}

// ---------------------------------------------------------------------------
// Per-row: merge 32 slots -> winner + runner-up -> margin; flag tight rows.
// ---------------------------------------------------------------------------
__global__ __launch_bounds__(256) void finalize1(
    const unsigned long long* __restrict__ cand1,
    const unsigned int* __restrict__ cand2, int* __restrict__ idxi,
    unsigned int* __restrict__ flags, unsigned int* __restrict__ flag_count,
    unsigned int* __restrict__ flag_list) {
  int row = blockIdx.x * 256 + threadIdx.x;
  unsigned long long best = 0;
  unsigned int second = 0;
  int bslot = 0;
#pragma unroll
  for (int s = 0; s < 32; ++s) {
    unsigned long long v = cand1[(size_t)row * 32 + s];
    unsigned int vs = (unsigned int)(v >> 32);
    if (v > best) {
      second = (unsigned int)(best >> 32);
      best = v;
      bslot = s;
    } else if (vs > second) {
      second = vs;
    }
  }
  unsigned int r2 = cand2[(size_t)row * 32 + bslot];
  if (r2 > second) second = r2;
  float s1 = funord((unsigned int)(best >> 32));
  float s2 = funord(second);
  int idx = NEMB - 1 - (int)(best & 0xFFFFFFFFull);
  idxi[row] = idx;
  unsigned int fl = ((s1 - s2) < TAU) ? 1u : 0u;
  flags[row] = fl;
  if (fl) {
    unsigned int p = atomicAdd(flag_count, 1u);
    flag_list[p] = row;
  }
}

// ---------------------------------------------------------------------------
// Exact fp32 rescore of flagged rows. Block owns 32 codes in registers,
// z row in staggered LDS (conflict-free b128), 2 rows/iter, shuffle reduce,
// one packed atomicMax per row.
// ---------------------------------------------------------------------------
__global__ __launch_bounds__(256) void rescore(
    const float* __restrict__ z, const float* __restrict__ emb,
    const float* __restrict__ inv_norm,
    const unsigned int* __restrict__ flag_list,
    const unsigned int* __restrict__ flag_count,
    unsigned long long* __restrict__ packed_rescore) {
  __shared__ float z_s[2][292];
  __shared__ unsigned long long red[64];
  const int tid = threadIdx.x;
  const int l = tid & 63;
  const int w = tid >> 6;
  const int cl = l & 7;
  const int p = l >> 3;
  const int code = w * 8 + cl;
  const int cbase = blockIdx.x * 32;

  float4 e4[8];
  const float* ebase = emb + (size_t)(cbase + code) * 256 + p * 32;
#pragma unroll
  for (int j = 0; j < 8; ++j) e4[j] = *(const float4*)&ebase[4 * j];
  const float inv = inv_norm[cbase + code];
  const unsigned int lowbits = (unsigned int)(NEMB - 1 - (cbase + code));

  unsigned int cnt = *flag_count;
  for (unsigned int f = 0; f < cnt; f += 2) {
    int row0 = (int)flag_list[f];
    int row1 = (f + 1 < cnt) ? (int)flag_list[f + 1] : row0;
    __syncthreads();
    if (tid < 128) {
      int half = tid >> 6, t = tid & 63;
      int k0 = t * 4;
      int addr = k0 + 4 * (k0 >> 5);
      const float* zp = z + (size_t)(half ? row1 : row0) * 256 + k0;
      *(float4*)&z_s[half][addr] = *(const float4*)zp;
    }
    __syncthreads();
    float a0 = 0.f, a1 = 0.f;
#pragma unroll
    for (int j = 0; j < 8; ++j) {
      float4 z0 = *(const float4*)&z_s[0][p * 36 + 4 * j];
      float4 z1 = *(const float4*)&z_s[1][p * 36 + 4 * j];
      a0 += e4[j].x * z0.x + e4[j].y * z0.y + e4[j].z * z0.z + e4[j].w * z0.w;
      a1 += e4[j].x * z1.x + e4[j].y * z1.y + e4[j].z * z1.z + e4[j].w * z1.w;
    }
#pragma unroll
    for (int m = 8; m < 64; m <<= 1) {
      a0 += __shfl_xor(a0, m);
      a1 += __shfl_xor(a1, m);
    }
    if (l < 8)
      red[w * 8 + cl] = ((unsigned long long)ford(a0 * inv) << 32) | lowbits;
    else if (l < 16)
      red[32 + w * 8 + cl] = ((unsigned long long)ford(a1 * inv) << 32) | lowbits;
    __syncthreads();
    if (w == 0) {
      unsigned long long v = red[l];
#pragma unroll
      for (int m = 1; m < 32; m <<= 1) {
        unsigned long long o = __shfl_xor(v, m);
        if (o > v) v = o;
      }
      if (l == 0) atomicMax(&packed_rescore[row0], v);
      if (l == 32) atomicMax(&packed_rescore[row1], v);
    }
  }
}

// ---------------------------------------------------------------------------
// Final idx (float) + z_q gather. One wave per row.
// ---------------------------------------------------------------------------
__global__ __launch_bounds__(256) void gather_out(
    const int* __restrict__ idxi, const unsigned int* __restrict__ flags,
    const unsigned long long* __restrict__ packed_rescore,
    const float* __restrict__ emb, float* __restrict__ zq,
    float* __restrict__ idx_out) {
  int row = blockIdx.x * 4 + (threadIdx.x >> 6);
  int lane = threadIdx.x & 63;
  int idx = idxi[row];
  if (flags[row])
    idx = NEMB - 1 - (int)(packed_rescore[row] & 0xFFFFFFFFull);
  if (lane == 0) idx_out[row] = (float)idx;
  const float4* src = (const float4*)(emb + (size_t)idx * 256);
  float4* dst = (float4*)(zq + (size_t)row * 256);
  dst[lane] = src[lane];
}

// ---------------------------------------------------------------------------
extern "C" void kernel_launch(void* const* d_in, const int* in_sizes, int n_in,
                              void* d_out, int out_size, void* d_ws,
                              size_t ws_size, hipStream_t stream) {
  (void)in_sizes; (void)n_in; (void)out_size; (void)ws_size;
  const float* x     = (const float*)d_in[0];
  const float* enc_w = (const float*)d_in[1];
  const float* enc_b = (const float*)d_in[2];
  const float* emb   = (const float*)d_in[3];
  const float* dec_w = (const float*)d_in[4];
  const float* dec_b = (const float*)d_in[5];

  float* out     = (float*)d_out;
  float* x_recon = out;                               // 8192*1024
  float* z_out   = x_recon + (size_t)BATCH * IN_DIM;  // 8192*256
  float* zq_out  = z_out + (size_t)BATCH * LAT;       // 8192*256
  float* idx_out = zq_out + (size_t)BATCH * LAT;      // 8192 (as float)

  char* ws = (char*)d_ws;
  float* inv_norm = (float*)ws;                                    // 32 KB
  unsigned int* flags = (unsigned int*)(ws + 32768);               // 32 KB
  int* idxi = (int*)(ws + 65536);                                  // 32 KB
  unsigned int* flag_count = (unsigned int*)(ws + 98304);          // (zeroed)
  unsigned long long* packed_rescore =
      (unsigned long long*)(ws + 98432);                           // 64 KB (zeroed)
  unsigned int* flag_list = (unsigned int*)(ws + 163968);          // 32 KB
  unsigned long long* cand1 = (unsigned long long*)(ws + 262144);  // 2 MB (8192x32)
  unsigned int* cand2 = (unsigned int*)(ws + 2359296);             // 1 MB
  _Float16* wfrag  = (_Float16*)(ws + 3407872);                    // 1 MB hi+lo
  _Float16* dwfrag = (_Float16*)(ws + 4456448);                    // 1 MB hi+lo
  _Float16* efrag  = (_Float16*)(ws + 5505024);                    // 4 MB hi only
  _Float16* zfrag  = (_Float16*)(ws + 9699328);                    // 8 MB hi+lo

  hipMemsetAsync(ws + 98304, 0, 128 + 65536, stream);

  emb_norms<<<NEMB / 4, 256, 0, stream>>>(emb, inv_norm);
  split16<<<128, 256, 0, stream>>>(enc_w, (const float*)nullptr, wfrag,
                                   (size_t)LAT * IN_DIM, IN_DIM / 16, 1);
  split16<<<128, 256, 0, stream>>>(dec_w, (const float*)nullptr, dwfrag,
                                   (size_t)IN_DIM * LAT, LAT / 16, 1);
  split16<<<1024, 256, 0, stream>>>(emb, inv_norm, efrag, 0, LAT / 16, 0);

  // encoder: z = x @ enc_w^T + enc_b   (32x128 blocks, wfrag L2-resident)
  gemm16s<<<dim3(LAT / 128, BATCH / 32), 256, 0, stream>>>(
      x, wfrag, (size_t)LAT * IN_DIM, enc_b, z_out, LAT, IN_DIM);

  split16<<<1024, 256, 0, stream>>>(z_out, (const float*)nullptr, zfrag,
                                    (size_t)BATCH * LAT, LAT / 16, 1);

  // fused score + top-2 argmax (XCD-grouped csplit)
  score_mfma<<<1024, 256, 0, stream>>>(zfrag, efrag, cand1, cand2);

  finalize1<<<32, 256, 0, stream>>>(cand1, cand2, idxi, flags, flag_count,
                                    flag_list);
  rescore<<<256, 256, 0, stream>>>(z_out, emb, inv_norm, flag_list, flag_count,
                                   packed_rescore);
  gather_out<<<BATCH / 4, 256, 0, stream>>>(idxi, flags, packed_rescore, emb,
                                            zq_out, idx_out);

  // decoder: x_recon = z_q @ dec_w^T + dec_b  (dwfrag L2-resident)
  gemm16s<<<dim3(IN_DIM / 128, BATCH / 32), 256, 0, stream>>>(
      zq_out, dwfrag, (size_t)IN_DIM * LAT, dec_b, x_recon, IN_DIM, LAT);
}